// Round 6
// baseline (164.132 us; speedup 1.0000x reference)
//
#include <hip/hip_runtime.h>
#include <stdint.h>

// FC tensor product as on-the-fly-A GEMMs, f16, MFMA f32_16x16x32_f16.
// A[r,(u,v)] = a[r,u]*b[r,v]: b octets in registers all phase (u-independent),
// W pairs (K=64) stream through 4 LDS pair-slots with counted vmcnt.
// W octets for macro t+1 are prefetched into registers via VOLATILE inline-asm
// ds_read_b128 (compiler cannot sink them), with counted lgkmcnt(8) before the
// MFMA cluster -> MFMAs never wait on LDS latency. Epilogue: f32 atomicAdd
// into a pre-zeroed out (no slabs / no ep_add pass).

typedef _Float16 f16;
typedef f16 f16x8 __attribute__((ext_vector_type(8)));
typedef float f32x4 __attribute__((ext_vector_type(4)));
typedef int i32x4 __attribute__((ext_vector_type(4)));

#define OFF_W000 0u
#define OFF_W110 2097152u
#define OFF_W011 2621440u
#define OFF_W101 3145728u
#define OFF_W111 3670016u        // size 262144 (64*64*64)
#define OFF_XS1  3932160u
#define OFF_XS2  4980736u
#define OFF_XV1  6029312u
#define OFF_XV2  7602176u
#define WS_ELEMS 9175040u

#define SC_0E 0.006987712429686843f
#define SC_1O 0.0078125f
#define SC_1E 0.011048543456039806f

// ---------------- pre-kernel: retile everything to f16 ----------------
// total threads = 9175040 = 35840 blocks * 256 (exact; every branch bound exact)
__global__ void tile_all_k(const float* __restrict__ w000, const float* __restrict__ w011,
                           const float* __restrict__ w101, const float* __restrict__ w110,
                           const float* __restrict__ w111, const float* __restrict__ x1,
                           const float* __restrict__ x2, f16* __restrict__ ws)
{
  unsigned tid = blockIdx.x*256u + threadIdx.x;
  if (tid < 2097152u) {  // W000t [vh][u][p][q][n128][8]
    unsigned e=tid&7u, n=(tid>>3)&127u, q=(tid>>10)&3u, p=(tid>>12)&1u, u=(tid>>13)&127u, vh=(tid>>20)&1u;
    unsigned v = vh*64u + p*32u + q*8u + e;
    ws[OFF_W000+tid] = (f16)w000[u*16384u + v*128u + n];
    return;
  }
  tid -= 2097152u;
  if (tid < 524288u) {   // W110t [u64][p][q][n128][8], fold 1/sqrt3
    unsigned e=tid&7u, n=(tid>>3)&127u, q=(tid>>10)&3u, p=(tid>>12)&1u, u=tid>>13;
    unsigned v = p*32u + q*8u + e;
    ws[OFF_W110+tid] = (f16)(w110[u*8192u + v*128u + n] * 0.5773502691896258f);
    return;
  }
  tid -= 524288u;
  if (tid < 524288u) {   // W011t [u128][p][q][n64][8]
    unsigned e=tid&7u, n=(tid>>3)&63u, q=(tid>>9)&3u, p=(tid>>11)&1u, u=tid>>12;
    unsigned v = p*32u + q*8u + e;
    ws[OFF_W011+tid] = (f16)w011[u*4096u + v*64u + n];
    return;
  }
  tid -= 524288u;
  if (tid < 524288u) {   // W101t [u=s2 128][p][q][n64][8]  (transposed)
    unsigned e=tid&7u, n=(tid>>3)&63u, q=(tid>>9)&3u, p=(tid>>11)&1u, u=tid>>12;
    unsigned v = p*32u + q*8u + e;   // v1 index
    ws[OFF_W101+tid] = (f16)w101[v*8192u + u*64u + n];
    return;
  }
  tid -= 524288u;
  if (tid < 262144u) {   // W111t [u64][p][q][n64][8]  (exact size 64*64*64)
    unsigned e=tid&7u, n=(tid>>3)&63u, q=(tid>>9)&3u, p=(tid>>11)&1u, u=tid>>12;
    unsigned v = p*32u + q*8u + e;
    ws[OFF_W111+tid] = (f16)w111[u*4096u + v*64u + n];
    return;
  }
  tid -= 262144u;
  if (tid < 1048576u) {  // xs1 [rt][uo16][r128][8]
    unsigned e=tid&7u, r=(tid>>3)&127u, uo=(tid>>10)&15u, rt=tid>>14;
    ws[OFF_XS1+tid] = (f16)x1[(rt*128u+r)*320u + uo*8u + e];
    return;
  }
  tid -= 1048576u;
  if (tid < 1572864u) {  // xv1 [rt][i3][ov8][r128][8]
    unsigned e=tid&7u, r=(tid>>3)&127u, ov=(tid>>10)&7u, rest=tid>>13;
    unsigned i=rest%3u, rt=rest/3u;
    ws[OFF_XV1+tid] = (f16)x1[(rt*128u+r)*320u + 128u + (ov*8u+e)*3u + i];
    return;
  }
  tid -= 1572864u;
  if (tid < 1048576u) {  // xs2
    unsigned e=tid&7u, r=(tid>>3)&127u, uo=(tid>>10)&15u, rt=tid>>14;
    ws[OFF_XS2+tid] = (f16)x2[(rt*128u+r)*320u + uo*8u + e];
    return;
  }
  tid -= 1048576u;
  {                      // xv2 (exactly 1572864 remain)
    unsigned e=tid&7u, r=(tid>>3)&127u, ov=(tid>>10)&7u, rest=tid>>13;
    unsigned i=rest%3u, rt=rest/3u;
    ws[OFF_XV2+tid] = (f16)x2[(rt*128u+r)*320u + 128u + (ov*8u+e)*3u + i];
  }
}

// ---------------- zero cols [0,320) of out (atomic targets) ----------------
__global__ void zero_k(float* __restrict__ out)
{
  unsigned tid = blockIdx.x*256u + threadIdx.x;   // 655360 threads exactly
  unsigned r = tid/80u, c = tid - r*80u;
  *(f32x4*)(out + r*512u + c*4u) = (f32x4){0.f,0.f,0.f,0.f};
}

// ---------------- main kernel ----------------
#define GLD16(g,l) __builtin_amdgcn_global_load_lds( \
    (const __attribute__((address_space(1))) unsigned int*)(g), \
    (__attribute__((address_space(3))) unsigned int*)(l), 16, 0, 0)

#define WAITV(n) asm volatile("s_waitcnt vmcnt(" #n ")" ::: "memory")

__device__ __forceinline__ unsigned lds_off(const f16* p){
  return (unsigned)(unsigned long long)(__attribute__((address_space(3))) const f16*)p;
}
// volatile asm ds_read_b128: cannot be sunk/deleted by the compiler
template<int OFF>
__device__ __forceinline__ f16x8 ds128(unsigned a){
  f16x8 r;
  asm volatile("ds_read_b128 %0, %1 offset:%2" : "=v"(r) : "v"(a), "i"(OFF));
  return r;
}
__device__ __forceinline__ f16x8 ds128v(unsigned a){
  f16x8 r;
  asm volatile("ds_read_b128 %0, %1" : "=v"(r) : "v"(a));
  return r;
}

// 8 W-octets of pair-slot SL -> dst regs (issue only; no wait)
#define READ8(dst, SL) do{                                \
    dst[0]=ds128<(SL)*PAIRB+0*TILEB>(wbase[0]);           \
    dst[1]=ds128<(SL)*PAIRB+0*TILEB>(wbase[1]);           \
    dst[2]=ds128<(SL)*PAIRB+0*TILEB>(wbase[2]);           \
    dst[3]=ds128<(SL)*PAIRB+0*TILEB>(wbase[3]);           \
    dst[4]=ds128<(SL)*PAIRB+1*TILEB>(wbase[0]);           \
    dst[5]=ds128<(SL)*PAIRB+1*TILEB>(wbase[1]);           \
    dst[6]=ds128<(SL)*PAIRB+1*TILEB>(wbase[2]);           \
    dst[7]=ds128<(SL)*PAIRB+1*TILEB>(wbase[3]);           \
  }while(0)

// One pair-macro (K=64, 32 MFMA). kc compile-time. Steady lgkm FIFO:
// entering macro t the 8 reads R(t) (issued at t-1) are outstanding; we issue
// aR (kc==0) + R(t+1), then lgkmcnt(8) drains R(t)+aR, leaving R(t+1).
#define K_STEP(KC)                                                            \
  {                                                                           \
    constexpr int kc = (KC);                                                  \
    const int t = ss*8 + kc;                                                  \
    if (t + 2 < M) { if constexpr (S==1) WAITV(2); else WAITV(4); }           \
    else           WAITV(0);                                                  \
    __builtin_amdgcn_s_barrier();                                             \
    __builtin_amdgcn_sched_barrier(0);                                        \
    if (kc == 6 && ss+1 < SS) stA(ss+1);                                      \
    if (t + 3 < M) stPair(t+3, (kc+3)&3);                                     \
    if (kc == 0) {                                                            \
      const unsigned ao = (unsigned)((ss&1)<<10);                             \
      aR[0]=ds128v(abase[0]+ao); aR[1]=ds128v(abase[1]+ao);                   \
      aR[2]=ds128v(abase[2]+ao); aR[3]=ds128v(abase[3]+ao);                   \
    }                                                                         \
    if (!(kc==7 && ss+1>=SS)) {                                               \
      constexpr int SL = (kc+1)&3;                                            \
      if constexpr ((kc&1)==0) { READ8(bwB, SL); } else { READ8(bwA, SL); }   \
    }                                                                         \
    __builtin_amdgcn_sched_barrier(0);                                        \
    if (kc==7 && ss+1>=SS) { asm volatile("s_waitcnt lgkmcnt(0)":::"memory");}\
    else                   { asm volatile("s_waitcnt lgkmcnt(8)":::"memory");}\
    __builtin_amdgcn_sched_barrier(0);                                        \
    const f16x8 (&bw)[8] = (kc&1) ? bwB : bwA;                                \
    __builtin_amdgcn_s_setprio(1);                                            \
    _Pragma("unroll")                                                         \
    for (int tt=0; tt<2; ++tt) {                                              \
      f16x8 af[4];                                                            \
      _Pragma("unroll")                                                       \
      for (int mt=0; mt<4; ++mt) {                                            \
        f16 av = aR[mt][kc];                                                  \
        if constexpr (NEG) av = -av;                                          \
        af[mt] = av * br[mt][tt];                                             \
      }                                                                       \
      _Pragma("unroll")                                                       \
      for (int nt=0; nt<4; ++nt)                                              \
        _Pragma("unroll")                                                     \
        for (int mt=0; mt<4; ++mt)                                            \
          acc[mt][nt] = __builtin_amdgcn_mfma_f32_16x16x32_f16(af[mt], bw[tt*4+nt], acc[mt][nt], 0,0,0); \
    }                                                                         \
    __builtin_amdgcn_s_setprio(0);                                            \
  }

template<int N, bool NEG, int SS>   // N = W tile col count (128 or 64)
__device__ __forceinline__ void run_phase(const f16* __restrict__ Wt,
    const f16* __restrict__ aW, const f16* __restrict__ bW, int bRow, int h,
    f16* sW, f16* sAw, f32x4 (&acc)[4][4])
{
  constexpr int S     = N/64;      // GLD16 issues per wave per tile
  constexpr int TILEB = N*64;      // tile bytes
  constexpr int PAIRB = 2*TILEB;   // pair bytes
  constexpr int M     = SS*8;      // pair-macros
  const int lane = threadIdx.x & 63, wid = threadIdx.x >> 6;
  const int q = lane >> 4, r15 = lane & 15;

  WAITV(0);   // clear outstanding vmem from prior phase for exact counting

  // b octets for the whole phase -> registers (u-independent)
  f16x8 br[4][2];
#pragma unroll
  for (int mt=0; mt<4; ++mt)
#pragma unroll
    for (int o=0; o<2; ++o)
      br[mt][o] = *(const f16x8*)(bW + (o*4+q)*1024 + (bRow + mt*16 + r15)*8);
#pragma unroll
  for (int mt=0; mt<4; ++mt)
#pragma unroll
    for (int o=0; o<2; ++o) {      // force loads complete now (vmcnt -> 0)
      i32x4 tmp = __builtin_bit_cast(i32x4, br[mt][o]);
      asm volatile("" :: "v"(tmp));
    }

  const int wchunk = wid*S*1024;
  auto stPair = [&](int p, int slot){
    const char* s = (const char*)Wt + (size_t)p*PAIRB + wchunk;
    char* d = (char*)sW + slot*PAIRB + wchunk;
#pragma unroll
    for (int tt=0; tt<2; ++tt)
#pragma unroll
      for (int c=0; c<S; ++c)
        GLD16(s + tt*TILEB + c*1024 + lane*16, d + tt*TILEB + c*1024);
  };
  auto stA = [&](int ss2){   // 1KB a-chunk for superstep ss2 into per-wave slot
    GLD16((const char*)(aW + ss2*1024) + lane*16, (char*)sAw + (ss2&1)*1024);
  };

  // lane-fixed LDS byte addresses for the asm reads
  unsigned wbase[4], abase[4];
#pragma unroll
  for (int nt=0; nt<4; ++nt)
    wbase[nt] = lds_off(sW + (q*N + h*64 + nt*16 + r15)*8);
#pragma unroll
  for (int mt=0; mt<4; ++mt)
    abase[mt] = lds_off(sAw + (mt*16 + r15)*8);

  // prologue: 3 pairs + a-chunk 0 in flight; drain stA+P(0), keep P(1),P(2)
  stA(0); stPair(0,0); stPair(1,1); stPair(2,2);
  if constexpr (S==1) WAITV(4); else WAITV(8);
  __builtin_amdgcn_s_barrier();
  __builtin_amdgcn_sched_barrier(0);

  f16x8 bwA[8], bwB[8];      // W octets, double-buffered by macro parity
  f16x8 aR[4];
  READ8(bwA, 0);             // R(0): slot 0 resident

#pragma unroll 1
  for (int ss = 0; ss < SS; ++ss) {
    K_STEP(0) K_STEP(1) K_STEP(2) K_STEP(3)
    K_STEP(4) K_STEP(5) K_STEP(6) K_STEP(7)
  }
  __builtin_amdgcn_s_barrier();     // protect sW/sA before next phase / epilogue
  __builtin_amdgcn_sched_barrier(0);
}

__global__ __launch_bounds__(256, 2)
void tp_main(f16* __restrict__ ws, float* __restrict__ out)
{
  __shared__ f16 smem[36864];       // 72KB: sW 4 pair-slots x 16KB | per-wave a 2x1KB
  f16* sW = smem;
  const int lane = threadIdx.x & 63, wid = threadIdx.x >> 6;
  f16* sAw = smem + 32768 + wid*1024;
  const int q = lane >> 4, r15 = lane & 15;

  f32x4 acc[4][4];
#pragma unroll
  for (int a=0;a<4;++a)
#pragma unroll
    for (int b=0;b<4;++b) acc[a][b] = (f32x4){0.f,0.f,0.f,0.f};

  const int bid = blockIdx.x;

  if (bid < 128) {          // ---- J0a: w000, K-half vh. waves: 2 rgrp x 2 h
    const int rt = bid >> 1, vh = bid & 1;
    const int rgrp = wid >> 1, h = wid & 1;
    const f16* aW = ws + OFF_XS1 + rt*16384 + rgrp*512;
    const f16* bW = ws + OFF_XS2 + rt*16384 + vh*8192;
    run_phase<128,false,16>(ws + OFF_W000 + vh*1048576u, aW, bW, rgrp*64, h, sW, sAw, acc);
    const int rowb = rt*128 + rgrp*64;
#pragma unroll
    for (int mt=0;mt<4;++mt)
#pragma unroll
      for (int nt=0;nt<4;++nt)
#pragma unroll
        for (int rg=0;rg<4;++rg)
          atomicAdd(out + (rowb+mt*16+q*4+rg)*512 + h*64+nt*16+r15, SC_0E*acc[mt][nt][rg]);
  } else if (bid < 224) {   // ---- J1o-a: w011 (a=s1, b=v2_i), 4 row-groups
    const int id = bid-128, i = id%3, rt = id/3;
    const int rgrp = wid, ro = rgrp & 1, sub = rgrp >> 1;
    const int rtt = rt*2 + sub;
    const f16* aW = ws + OFF_XS1 + rtt*16384 + ro*512;
    const f16* bW = ws + OFF_XV2 + (rtt*3+i)*8192;
    run_phase<64,false,16>(ws + OFF_W011, aW, bW, ro*64, 0, sW, sAw, acc);
    const int rowb = rt*256 + rgrp*64;
#pragma unroll
    for (int mt=0;mt<4;++mt)
#pragma unroll
      for (int nt=0;nt<4;++nt)
#pragma unroll
        for (int rg=0;rg<4;++rg)
          atomicAdd(out + (rowb+mt*16+q*4+rg)*512 + 128 + 3*(nt*16+r15) + i, SC_1O*acc[mt][nt][rg]);
  } else if (bid < 320) {   // ---- J1o-b: w101 (a=s2, b=v1_i)
    const int id = bid-224, i = id%3, rt = id/3;
    const int rgrp = wid, ro = rgrp & 1, sub = rgrp >> 1;
    const int rtt = rt*2 + sub;
    const f16* aW = ws + OFF_XS2 + rtt*16384 + ro*512;
    const f16* bW = ws + OFF_XV1 + (rtt*3+i)*8192;
    run_phase<64,false,16>(ws + OFF_W101, aW, bW, ro*64, 0, sW, sAw, acc);
    const int rowb = rt*256 + rgrp*64;
#pragma unroll
    for (int mt=0;mt<4;++mt)
#pragma unroll
      for (int nt=0;nt<4;++nt)
#pragma unroll
        for (int rg=0;rg<4;++rg)
          atomicAdd(out + (rowb+mt*16+q*4+rg)*512 + 128 + 3*(nt*16+r15) + i, SC_1O*acc[mt][nt][rg]);
  } else if (bid < 416) {   // ---- J1e: w111 cross component kk (two signed terms)
    const int id = bid-320, kk = id%3, rt = id/3;
    int i = kk+1; if (i>2) i-=3;
    int j = kk+2; if (j>2) j-=3;
    const int rgrp = wid, ro = rgrp & 1, sub = rgrp >> 1;
    const int rtt = rt*2 + sub;
    run_phase<64,false,8>(ws + OFF_W111,
        ws + OFF_XV1 + (rtt*3+i)*8192 + ro*512, ws + OFF_XV2 + (rtt*3+j)*8192,
        ro*64, 0, sW, sAw, acc);
    run_phase<64,true,8>(ws + OFF_W111,
        ws + OFF_XV1 + (rtt*3+j)*8192 + ro*512, ws + OFF_XV2 + (rtt*3+i)*8192,
        ro*64, 0, sW, sAw, acc);
    const int rowb = rt*256 + rgrp*64;
#pragma unroll
    for (int mt=0;mt<4;++mt)
#pragma unroll
      for (int nt=0;nt<4;++nt)
#pragma unroll
        for (int rg=0;rg<4;++rg)
          out[(rowb+mt*16+q*4+rg)*512 + 320 + 3*(nt*16+r15) + kk] = SC_1E*acc[mt][nt][rg];
  } else {                  // ---- J0b: w110' (v1_i x v2_i), two rt per block
    const int id = bid-416, i = id%3, rp = id/3;
    const int rgrp = wid >> 1, h = wid & 1;
#pragma unroll 1
    for (int hh = 0; hh < 2; ++hh) {
      const int rt = rp*2 + hh;
      const f16* aW = ws + OFF_XV1 + (rt*3+i)*8192 + rgrp*512;
      const f16* bW = ws + OFF_XV2 + (rt*3+i)*8192;
      run_phase<128,false,8>(ws + OFF_W110, aW, bW, rgrp*64, h, sW, sAw, acc);
      const int rowb = rt*128 + rgrp*64;
#pragma unroll
      for (int mt=0;mt<4;++mt)
#pragma unroll
        for (int nt=0;nt<4;++nt)
#pragma unroll
          for (int rg=0;rg<4;++rg) {
            atomicAdd(out + (rowb+mt*16+q*4+rg)*512 + h*64+nt*16+r15, SC_0E*acc[mt][nt][rg]);
            acc[mt][nt][rg] = 0.f;
          }
    }
  }
}

extern "C" void kernel_launch(void* const* d_in, const int* in_sizes, int n_in,
                              void* d_out, int out_size, void* d_ws, size_t ws_size,
                              hipStream_t stream)
{
  const float* x1   = (const float*)d_in[0];
  const float* x2   = (const float*)d_in[1];
  const float* w000 = (const float*)d_in[2];
  const float* w011 = (const float*)d_in[3];
  const float* w101 = (const float*)d_in[4];
  const float* w110 = (const float*)d_in[5];
  const float* w111 = (const float*)d_in[6];
  float* out = (float*)d_out;
  f16* ws   = (f16*)d_ws;

  if (ws_size < (size_t)WS_ELEMS * 2) return;   // ~18.4 MB scratch

  tile_all_k<<<35840, 256, 0, stream>>>(w000, w011, w101, w110, w111, x1, x2, ws);
  zero_k<<<2560, 256, 0, stream>>>(out);
  tp_main<<<512, 256, 0, stream>>>(ws, out);
}

// Round 7
// 157.599 us; speedup vs baseline: 1.0414x; 1.0414x over previous
//
#include <hip/hip_runtime.h>
#include <stdint.h>

// FC tensor product as on-the-fly-A GEMMs, f16, MFMA f32_16x16x32_f16.
// BARRIER-FREE main loop: all LDS is wave-private (2x8KB W slots + 2x1KB a
// slots per wave). Each wave streams its own W pairs via global_load_lds with
// per-wave counted vmcnt (8/9, never 0 in-loop). No s_barrier anywhere in the
// K-loop -> waves self-pace and decorrelate, covering each other's bubbles.
// All phases N=64. Epilogue: f16 partial slabs + ep_add (R4-proven).

typedef _Float16 f16;
typedef f16 f16x8 __attribute__((ext_vector_type(8)));
typedef float f32x4 __attribute__((ext_vector_type(4)));
typedef int i32x4 __attribute__((ext_vector_type(4)));

#define OFF_W000 0u               // [h2][vh2][u128][p2][q4][n64][8]
#define OFF_W110 2097152u         // [h2][u64][p2][q4][n64][8]
#define OFF_W011 2621440u         // [u128][p][q][n64][8]
#define OFF_W101 3145728u         // [u=s2 128][p][q][n64][8]
#define OFF_W111 3670016u         // [u64][p][q][n64][8]
#define OFF_XS1  3932160u         // [rt64][uo16][r128][8]
#define OFF_XS2  4980736u
#define OFF_XV1  6029312u         // [rt][i3][ov8][r128][8]
#define OFF_XV2  7602176u
#define OFF_S0A  9175040u
#define OFF_S0B  10223616u
#define OFF_S1O  13369344u
#define WS_ELEMS 14942208u

#define SC_0E 0.006987712429686843f
#define SC_1O 0.0078125f
#define SC_1E 0.011048543456039806f

// ---------------- pre-kernel: retile everything to f16 ----------------
// total threads = 9175040 = 35840 blocks * 256 (every branch bound exact)
__global__ void tile_all_k(const float* __restrict__ w000, const float* __restrict__ w011,
                           const float* __restrict__ w101, const float* __restrict__ w110,
                           const float* __restrict__ w111, const float* __restrict__ x1,
                           const float* __restrict__ x2, f16* __restrict__ ws)
{
  unsigned tid = blockIdx.x*256u + threadIdx.x;
  if (tid < 2097152u) {  // W000t [h][vh][u][p][q][n64][8]
    unsigned e=tid&7u, n=(tid>>3)&63u, q=(tid>>9)&3u, p=(tid>>11)&1u,
             u=(tid>>12)&127u, vh=(tid>>19)&1u, h=(tid>>20)&1u;
    unsigned v = vh*64u + p*32u + q*8u + e;
    ws[OFF_W000+tid] = (f16)w000[u*16384u + v*128u + h*64u + n];
    return;
  }
  tid -= 2097152u;
  if (tid < 524288u) {   // W110t [h][u64][p][q][n64][8], fold 1/sqrt3
    unsigned e=tid&7u, n=(tid>>3)&63u, q=(tid>>9)&3u, p=(tid>>11)&1u,
             u=(tid>>12)&63u, h=(tid>>18)&1u;
    unsigned v = p*32u + q*8u + e;
    ws[OFF_W110+tid] = (f16)(w110[u*8192u + v*128u + h*64u + n] * 0.5773502691896258f);
    return;
  }
  tid -= 524288u;
  if (tid < 524288u) {   // W011t [u128][p][q][n64][8]
    unsigned e=tid&7u, n=(tid>>3)&63u, q=(tid>>9)&3u, p=(tid>>11)&1u, u=tid>>12;
    unsigned v = p*32u + q*8u + e;
    ws[OFF_W011+tid] = (f16)w011[u*4096u + v*64u + n];
    return;
  }
  tid -= 524288u;
  if (tid < 524288u) {   // W101t [u=s2 128][p][q][n64][8]  (transposed)
    unsigned e=tid&7u, n=(tid>>3)&63u, q=(tid>>9)&3u, p=(tid>>11)&1u, u=tid>>12;
    unsigned v = p*32u + q*8u + e;   // v1 index
    ws[OFF_W101+tid] = (f16)w101[v*8192u + u*64u + n];
    return;
  }
  tid -= 524288u;
  if (tid < 262144u) {   // W111t [u64][p][q][n64][8]
    unsigned e=tid&7u, n=(tid>>3)&63u, q=(tid>>9)&3u, p=(tid>>11)&1u, u=tid>>12;
    unsigned v = p*32u + q*8u + e;
    ws[OFF_W111+tid] = (f16)w111[u*4096u + v*64u + n];
    return;
  }
  tid -= 262144u;
  if (tid < 1048576u) {  // xs1 [rt][uo16][r128][8]
    unsigned e=tid&7u, r=(tid>>3)&127u, uo=(tid>>10)&15u, rt=tid>>14;
    ws[OFF_XS1+tid] = (f16)x1[(rt*128u+r)*320u + uo*8u + e];
    return;
  }
  tid -= 1048576u;
  if (tid < 1572864u) {  // xv1 [rt][i3][ov8][r128][8]
    unsigned e=tid&7u, r=(tid>>3)&127u, ov=(tid>>10)&7u, rest=tid>>13;
    unsigned i=rest%3u, rt=rest/3u;
    ws[OFF_XV1+tid] = (f16)x1[(rt*128u+r)*320u + 128u + (ov*8u+e)*3u + i];
    return;
  }
  tid -= 1572864u;
  if (tid < 1048576u) {  // xs2
    unsigned e=tid&7u, r=(tid>>3)&127u, uo=(tid>>10)&15u, rt=tid>>14;
    ws[OFF_XS2+tid] = (f16)x2[(rt*128u+r)*320u + uo*8u + e];
    return;
  }
  tid -= 1048576u;
  {                      // xv2
    unsigned e=tid&7u, r=(tid>>3)&127u, ov=(tid>>10)&7u, rest=tid>>13;
    unsigned i=rest%3u, rt=rest/3u;
    ws[OFF_XV2+tid] = (f16)x2[(rt*128u+r)*320u + 128u + (ov*8u+e)*3u + i];
  }
}

// ---------------- main kernel ----------------
#define GLD16(g,l) __builtin_amdgcn_global_load_lds( \
    (const __attribute__((address_space(1))) unsigned int*)(g), \
    (__attribute__((address_space(3))) unsigned int*)(l), 16, 0, 0)

#define WAITV(n) asm volatile("s_waitcnt vmcnt(" #n ")" ::: "memory")

// One phase: acc += A*W.  SS supersteps x 8 macros; macro = K=64 (one u).
// Wave-private: W pair p -> slot p&1 (8KB); a-chunk ss -> slot ss&1 (1KB).
// Per-wave vmcnt FIFO at macro-t top: st(t)[8] (+stA) + st(t+1)[8].
//   kc<7:          WAITV(8)  (drains st(t), and stA when kc==0)
//   kc==7, !last:  WAITV(9)  (drains st(t), leaves stA+st(t+1))
//   kc==7, last:   WAITV(0)
// Issues at macro-t end (after all LDS reads of slot t&1): stA(ss+1) at kc==6,
// then st(t+2) into slot t&1. No barriers.
template<bool NEG, int SS>
__device__ __forceinline__ void run_phase(const f16* __restrict__ Wt,
    const f16* __restrict__ aW, const f16* __restrict__ bW, int bRow,
    f16* sWw, f16* sAw, f32x4 (&acc)[4][4], int lane)
{
  constexpr int M = SS*8;
  const int q = lane >> 4, r15 = lane & 15;

  // b octets for the whole phase -> registers (u-independent)
  f16x8 br[4][2];
#pragma unroll
  for (int mt=0; mt<4; ++mt)
#pragma unroll
    for (int o=0; o<2; ++o)
      br[mt][o] = *(const f16x8*)(bW + (o*4+q)*1024 + (bRow + mt*16 + r15)*8);
#pragma unroll
  for (int mt=0; mt<4; ++mt)
#pragma unroll
    for (int o=0; o<2; ++o) {      // force loads complete now (vmcnt -> 0)
      i32x4 tmp = __builtin_bit_cast(i32x4, br[mt][o]);
      asm volatile("" :: "v"(tmp));
    }

  auto stPair = [&](int p, int slot){    // 8KB pair -> private slot
    const char* s = (const char*)Wt + (size_t)p*8192;
    char* d = (char*)sWw + slot*8192;
#pragma unroll
    for (int c=0; c<8; ++c)
      GLD16(s + c*1024 + lane*16, d + c*1024);
  };
  auto stA = [&](int ss2){               // 1KB a-chunk -> private slot
    GLD16((const char*)(aW + ss2*1024) + lane*16, (char*)sAw + (ss2&1)*1024);
  };

  // prologue FIFO: st(0)[8], stA(0)[1], st(1)[8]
  stPair(0,0); stA(0); stPair(1,1);

  f16x8 aR[4];
#pragma unroll 1
  for (int ss = 0; ss < SS; ++ss) {
#pragma unroll
    for (int kc = 0; kc < 8; ++kc) {
      const int t = ss*8 + kc;
      if (kc == 7) { if (ss+1 < SS) { WAITV(9); } else { WAITV(0); } }
      else         { WAITV(8); }
      // ---- a octets for this superstep (stA drained by the kc==0 WAITV(8))
      if (kc == 0) {
#pragma unroll
        for (int mt=0; mt<4; ++mt)
          aR[mt] = *(const f16x8*)(sAw + (ss&1)*512 + (mt*16+r15)*8);
      }
      // ---- compute: 8 ds_read_b128 of slot kc&1 + 32 MFMA (compiler-sched)
      __builtin_amdgcn_s_setprio(1);
#pragma unroll
      for (int p=0; p<2; ++p) {
        f16x8 af[4];
#pragma unroll
        for (int mt=0; mt<4; ++mt) {
          f16 av = aR[mt][kc];
          if constexpr (NEG) av = -av;
          af[mt] = av * br[mt][p];
        }
#pragma unroll
        for (int nt=0; nt<4; ++nt) {
          f16x8 bw = *(const f16x8*)(sWw + (kc&1)*4096 + p*2048 + (q*64 + nt*16 + r15)*8);
#pragma unroll
          for (int mt=0; mt<4; ++mt)
            acc[mt][nt] = __builtin_amdgcn_mfma_f32_16x16x32_f16(af[mt], bw, acc[mt][nt], 0,0,0);
        }
      }
      __builtin_amdgcn_s_setprio(0);
      __builtin_amdgcn_sched_barrier(0);   // pin issues below all slot reads
      // ---- issues (FIFO: stA then stPair)
      if (kc == 6 && ss+1 < SS) stA(ss+1);
      if (t + 2 < M) stPair(t+2, kc&1);    // slot just finished being read
    }
  }
}

__global__ __launch_bounds__(256, 2)
void tp_main(f16* __restrict__ ws, float* __restrict__ out)
{
  __shared__ f16 smem[36864];   // 72KB: 4 waves x (2x8KB W | then 2x1KB a)
  const int lane = threadIdx.x & 63, wid = threadIdx.x >> 6;
  f16* sWw = smem + wid*8192;           // 16KB per wave (2 slots)
  f16* sAw = smem + 32768 + wid*1024;   // 2KB per wave
  const int q = lane >> 4, r15 = lane & 15;
  const int sub = wid >> 1, rh = wid & 1;   // wave -> row-tile half / row half

  f32x4 acc[4][4];
#pragma unroll
  for (int a=0;a<4;++a)
#pragma unroll
    for (int b=0;b<4;++b) acc[a][b] = (f32x4){0.f,0.f,0.f,0.f};

  const int bid = blockIdx.x;

#define STORE_DIRECT(base_col_expr, SC)                                   \
  _Pragma("unroll")                                                       \
  for (int mt=0;mt<4;++mt)                                                \
    _Pragma("unroll")                                                     \
    for (int nt=0;nt<4;++nt)                                              \
      _Pragma("unroll")                                                   \
      for (int rg=0;rg<4;++rg)                                            \
        out[(rowb+mt*16+q*4+rg)*512 + (base_col_expr)] = (SC)*acc[mt][nt][rg];

#define STORE_SLAB(slab, stride, col_expr, SC)                            \
  _Pragma("unroll")                                                       \
  for (int mt=0;mt<4;++mt)                                                \
    _Pragma("unroll")                                                     \
    for (int nt=0;nt<4;++nt)                                              \
      _Pragma("unroll")                                                   \
      for (int rg=0;rg<4;++rg)                                            \
        (slab)[(rowb+mt*16+q*4+rg)*(stride) + (col_expr)] = (f16)((SC)*acc[mt][nt][rg]);

  if (bid < 128) {          // ---- J0a: w000; rtp x vh(K-half) x h(n-half)
    const int rtp = bid >> 2, vh = (bid >> 1) & 1, h = bid & 1;
    const int rtt = rtp*2 + sub;
    const f16* aW = ws + OFF_XS1 + rtt*16384 + rh*512;
    const f16* bW = ws + OFF_XS2 + rtt*16384 + vh*8192;
    const f16* Wt = ws + OFF_W000 + h*1048576u + vh*524288u;
    run_phase<false,16>(Wt, aW, bW, rh*64, sWw, sAw, acc, lane);
    const int rowb = rtt*128 + rh*64;
    if (vh == 0) { STORE_DIRECT(h*64+nt*16+r15, SC_0E) }
    else { f16* slab = ws + OFF_S0A; STORE_SLAB(slab, 128, h*64+nt*16+r15, SC_0E) }
  } else if (bid < 224) {   // ---- J1o-a: w011 (a=s1, b=v2_i) -> direct out1o
    const int id = bid-128, i = id%3, rtp = id/3;
    const int rtt = rtp*2 + sub;
    const f16* aW = ws + OFF_XS1 + rtt*16384 + rh*512;
    const f16* bW = ws + OFF_XV2 + (rtt*3+i)*8192;
    run_phase<false,16>(ws + OFF_W011, aW, bW, rh*64, sWw, sAw, acc, lane);
    const int rowb = rtt*128 + rh*64;
    STORE_DIRECT(128 + 3*(nt*16+r15) + i, SC_1O)
  } else if (bid < 320) {   // ---- J1o-b: w101 (a=s2, b=v1_i) -> slab S1O
    const int id = bid-224, i = id%3, rtp = id/3;
    const int rtt = rtp*2 + sub;
    const f16* aW = ws + OFF_XS2 + rtt*16384 + rh*512;
    const f16* bW = ws + OFF_XV1 + (rtt*3+i)*8192;
    run_phase<false,16>(ws + OFF_W101, aW, bW, rh*64, sWw, sAw, acc, lane);
    const int rowb = rtt*128 + rh*64;
    f16* slab = ws + OFF_S1O;
    STORE_SLAB(slab, 192, 3*(nt*16+r15) + i, SC_1O)
  } else if (bid < 416) {   // ---- J1e: w111 cross component kk, 2 signed terms
    const int id = bid-320, kk = id%3, rtp = id/3;
    int i = kk+1; if (i>2) i-=3;
    int j = kk+2; if (j>2) j-=3;
    const int rtt = rtp*2 + sub;
    run_phase<false,8>(ws + OFF_W111,
        ws + OFF_XV1 + (rtt*3+i)*8192 + rh*512, ws + OFF_XV2 + (rtt*3+j)*8192,
        rh*64, sWw, sAw, acc, lane);
    run_phase<true,8>(ws + OFF_W111,
        ws + OFF_XV1 + (rtt*3+j)*8192 + rh*512, ws + OFF_XV2 + (rtt*3+i)*8192,
        rh*64, sWw, sAw, acc, lane);
    const int rowb = rtt*128 + rh*64;
    STORE_DIRECT(320 + 3*(nt*16+r15) + kk, SC_1E)
  } else {                  // ---- J0b: w110' component i, n-half h -> slab i
    const int id = bid-416, i = id%3, h = (id/3)&1, rtp = id/6;
    const int rtt = rtp*2 + sub;
    const f16* aW = ws + OFF_XV1 + (rtt*3+i)*8192 + rh*512;
    const f16* bW = ws + OFF_XV2 + (rtt*3+i)*8192;
    run_phase<false,8>(ws + OFF_W110 + h*262144u, aW, bW, rh*64, sWw, sAw, acc, lane);
    const int rowb = rtt*128 + rh*64;
    f16* slab = ws + OFF_S0B + (unsigned)i*1048576u;
    STORE_SLAB(slab, 128, h*64+nt*16+r15, SC_0E)
  }
#undef STORE_DIRECT
#undef STORE_SLAB
}

// ---------------- epilogue: fold f16 partial slabs into out ----------------
__global__ void ep_add(const f16* __restrict__ ws, float* __restrict__ out)
{
  unsigned tid = blockIdx.x*256u + threadIdx.x;
  if (tid < 1048576u) {
    unsigned r = tid>>7, c = tid&127u;
    float s = (float)ws[OFF_S0A+tid] + (float)ws[OFF_S0B+tid]
            + (float)ws[OFF_S0B+1048576u+tid] + (float)ws[OFF_S0B+2097152u+tid];
    out[r*512u+c] += s;
  } else {
    unsigned t2 = tid - 1048576u;
    unsigned r = t2/192u, c = t2 - r*192u;
    out[r*512u+128u+c] += (float)ws[OFF_S1O+t2];
  }
}

extern "C" void kernel_launch(void* const* d_in, const int* in_sizes, int n_in,
                              void* d_out, int out_size, void* d_ws, size_t ws_size,
                              hipStream_t stream)
{
  const float* x1   = (const float*)d_in[0];
  const float* x2   = (const float*)d_in[1];
  const float* w000 = (const float*)d_in[2];
  const float* w011 = (const float*)d_in[3];
  const float* w101 = (const float*)d_in[4];
  const float* w110 = (const float*)d_in[5];
  const float* w111 = (const float*)d_in[6];
  float* out = (float*)d_out;
  f16* ws   = (f16*)d_ws;

  if (ws_size < (size_t)WS_ELEMS * 2) return;   // ~29.9 MB scratch

  tile_all_k<<<35840, 256, 0, stream>>>(w000, w011, w101, w110, w111, x1, x2, ws);
  tp_main<<<608, 256, 0, stream>>>(ws, out);
  ep_add<<<10240, 256, 0, stream>>>(ws, out);
}